// Round 2
// baseline (2758.474 us; speedup 1.0000x reference)
//
#include <hip/hip_runtime.h>
#include <cstdint>
#include <cstddef>

// ---------------- problem constants ----------------
constexpr int BSZ = 32;      // batch
constexpr int T   = 1024;    // time
constexpr int ID  = 256;     // input dim
constexpr int MD  = 8;       // memory_d
constexpr int ORD = 256;     // order
constexpr int HID = 512;     // hidden
constexpr int BD  = BSZ * MD;   // 256 state rows total
constexpr int CH  = 64;         // chunk size
constexpr int NQ  = T / CH;     // 16 chunks
constexpr int DO  = MD * ORD;   // 2048
constexpr int OO  = ORD * ORD;  // 65536

// ---------------- workspace layout (floats) ----------------
// U2   : BD x T                  =   262144
// P    : CH x ORD                =    16384
// Ptri : CH x CH x ORD           =  1048576
// Apow : (CH+1) x ORD x ORD      =  4259840   (index 0 unused, 1..64 = A^e)
// Mq   : NQ x BD x ORD           =  1048576   (M_0..M_15, global rows)
// Lend : NQ x BD x ORD           =  1048576   (L[q, c=CH-1])
// mbuf : G x T x MD x ORD        (G chosen at runtime to fit ws_size)
constexpr size_t OFF_U2   = 0;
constexpr size_t OFF_P    = OFF_U2   + (size_t)BD * T;
constexpr size_t OFF_PTRI = OFF_P    + (size_t)CH * ORD;
constexpr size_t OFF_APOW = OFF_PTRI + (size_t)CH * CH * ORD;
constexpr size_t OFF_MQ   = OFF_APOW + (size_t)(CH + 1) * OO;
constexpr size_t OFF_LEND = OFF_MQ   + (size_t)NQ * BD * ORD;
constexpr size_t OFF_MBUF = OFF_LEND + (size_t)NQ * BD * ORD;

// ---------------- zero a float range ----------------
__global__ __launch_bounds__(256) void k_zero(float* __restrict__ p, int n) {
    int i = blockIdx.x * 256 + threadIdx.x;
    if (i < n) p[i] = 0.f;
}

// ---------------- K1: U2[bd][t] = x[b,t,:] . kernel[:,d] ----------------
__global__ __launch_bounds__(256) void k_u(const float* __restrict__ x,
                                           const float* __restrict__ kern,
                                           float* __restrict__ U2) {
    __shared__ float xs[32][ID + 1];
    __shared__ float ks[ID][MD];
    const int blk = blockIdx.x;
    const int b   = blk / (T / 32);
    const int t0  = (blk % (T / 32)) * 32;
    const int tid = threadIdx.x;

    for (int i = tid; i < ID * MD; i += 256) ks[i / MD][i % MD] = kern[i];
    const float* xp = x + ((size_t)b * T + t0) * ID;
    for (int i = tid; i < 32 * ID; i += 256) xs[i >> 8][i & 255] = xp[i];
    __syncthreads();

    const int d  = tid / 32;
    const int tl = tid % 32;
    float acc = 0.f;
    #pragma unroll 8
    for (int i = 0; i < ID; ++i) acc += xs[tl][i] * ks[i][d];
    U2[((size_t)b * MD + d) * T + t0 + tl] = acc;
}

// ---------------- copy A -> Apow[1] ----------------
__global__ __launch_bounds__(256) void k_copyA(const float* __restrict__ A,
                                               float* __restrict__ Apow) {
    int idx = blockIdx.x * 256 + threadIdx.x;
    Apow[OO + idx] = A[idx];
}

// ---------------- doubling: Apow[n+z+1] = Apow[z+1] @ Apow[n] ----------------
__global__ __launch_bounds__(256) void k_pow(float* __restrict__ Apow, int n) {
    __shared__ float As[16][65];
    __shared__ float Bs[16][65];
    const int z    = blockIdx.z;
    const int row0 = blockIdx.y * 64;
    const int col0 = blockIdx.x * 64;
    const int tid  = threadIdx.x;
    const int tx = tid & 15, ty = tid >> 4;
    const float* Ag = Apow + (size_t)(z + 1) * OO;
    const float* Bg = Apow + (size_t)n * OO;
    float*       Cg = Apow + (size_t)(n + z + 1) * OO;

    float acc[4][4] = {};
    for (int k0 = 0; k0 < ORD; k0 += 16) {
        for (int i = tid; i < 64 * 16; i += 256) {
            int m = i >> 4, kk = i & 15;
            As[kk][m] = Ag[(size_t)(row0 + m) * ORD + k0 + kk];
        }
        for (int i = tid; i < 16 * 64; i += 256) {
            int kk = i >> 6, n2 = i & 63;
            Bs[kk][n2] = Bg[(size_t)(k0 + kk) * ORD + col0 + n2];
        }
        __syncthreads();
        #pragma unroll
        for (int kk = 0; kk < 16; ++kk) {
            float a[4], b[4];
            #pragma unroll
            for (int i = 0; i < 4; ++i) a[i] = As[kk][ty * 4 + i];
            #pragma unroll
            for (int j = 0; j < 4; ++j) b[j] = Bs[kk][tx * 4 + j];
            #pragma unroll
            for (int i = 0; i < 4; ++i)
                #pragma unroll
                for (int j = 0; j < 4; ++j) acc[i][j] += a[i] * b[j];
        }
        __syncthreads();
    }
    #pragma unroll
    for (int i = 0; i < 4; ++i) {
        float4 v = make_float4(acc[i][0], acc[i][1], acc[i][2], acc[i][3]);
        *(float4*)&Cg[(size_t)(row0 + ty * 4 + i) * ORD + col0 + tx * 4] = v;
    }
}

// ---------------- P[k] = Brow @ A^k ----------------
__global__ __launch_bounds__(256) void k_p(const float* __restrict__ Brow,
                                           const float* __restrict__ Apow,
                                           float* __restrict__ P) {
    __shared__ float br[ORD];
    const int k = blockIdx.x;
    const int o = threadIdx.x;
    br[o] = Brow[o];
    __syncthreads();
    if (k == 0) { P[o] = br[o]; return; }
    const float* M = Apow + (size_t)k * OO;
    float acc = 0.f;
    #pragma unroll 4
    for (int op = 0; op < ORD; ++op) acc += br[op] * M[(size_t)op * ORD + o];
    P[(size_t)k * ORD + o] = acc;
}

// ---------------- Ptri[j][c][o] = (j<=c) ? P[c-j][o] : 0 ----------------
__global__ __launch_bounds__(256) void k_ptri(const float* __restrict__ P,
                                              float* __restrict__ Ptri) {
    int idx = blockIdx.x * 256 + threadIdx.x;   // CH*CH*ORD total
    int j = idx >> 14;
    int c = (idx >> 8) & (CH - 1);
    int o = idx & (ORD - 1);
    Ptri[idx] = (j <= c) ? P[(size_t)(c - j) * ORD + o] : 0.f;
}

// ---------------- Lend[q,bd,o] = sum_j U2[bd, qC+j] * P[CH-1-j, o] ----------------
__global__ __launch_bounds__(256) void k_lend(const float* __restrict__ U2,
                                              const float* __restrict__ P,
                                              float* __restrict__ Lend) {
    __shared__ float As[16][65];
    __shared__ float Bs[16][65];
    const int q    = blockIdx.z;
    const int row0 = blockIdx.y * 64;
    const int col0 = blockIdx.x * 64;
    const int tid  = threadIdx.x;
    const int tx = tid & 15, ty = tid >> 4;

    float acc[4][4] = {};
    for (int k0 = 0; k0 < CH; k0 += 16) {
        for (int i = tid; i < 64 * 16; i += 256) {
            int m = i >> 4, kk = i & 15;
            As[kk][m] = U2[(size_t)(row0 + m) * T + q * CH + k0 + kk];
        }
        for (int i = tid; i < 16 * 64; i += 256) {
            int kk = i >> 6, n2 = i & 63;
            Bs[kk][n2] = P[(size_t)(CH - 1 - (k0 + kk)) * ORD + col0 + n2];
        }
        __syncthreads();
        #pragma unroll
        for (int kk = 0; kk < 16; ++kk) {
            float a[4], b[4];
            #pragma unroll
            for (int i = 0; i < 4; ++i) a[i] = As[kk][ty * 4 + i];
            #pragma unroll
            for (int j = 0; j < 4; ++j) b[j] = Bs[kk][tx * 4 + j];
            #pragma unroll
            for (int i = 0; i < 4; ++i)
                #pragma unroll
                for (int j = 0; j < 4; ++j) acc[i][j] += a[i] * b[j];
        }
        __syncthreads();
    }
    #pragma unroll
    for (int i = 0; i < 4; ++i) {
        float4 v = make_float4(acc[i][0], acc[i][1], acc[i][2], acc[i][3]);
        *(float4*)&Lend[(size_t)q * (BD * ORD) +
                        (size_t)(row0 + ty * 4 + i) * ORD + col0 + tx * 4] = v;
    }
}

// ---------------- stage3: Mq[q+1] = Mq[q] @ A^CH + Lend[q] ----------------
__global__ __launch_bounds__(256) void k_stage3(float* __restrict__ Mq,
                                                const float* __restrict__ Apow,
                                                const float* __restrict__ Lend,
                                                int q) {
    __shared__ float As[16][65];
    __shared__ float Bs[16][65];
    const int row0 = blockIdx.y * 64;
    const int col0 = blockIdx.x * 64;
    const int tid  = threadIdx.x;
    const int tx = tid & 15, ty = tid >> 4;
    const float* Ag = Mq + (size_t)q * (BD * ORD);
    const float* Bg = Apow + (size_t)CH * OO;

    float acc[4][4] = {};
    for (int k0 = 0; k0 < ORD; k0 += 16) {
        for (int i = tid; i < 64 * 16; i += 256) {
            int m = i >> 4, kk = i & 15;
            As[kk][m] = Ag[(size_t)(row0 + m) * ORD + k0 + kk];
        }
        for (int i = tid; i < 16 * 64; i += 256) {
            int kk = i >> 6, n2 = i & 63;
            Bs[kk][n2] = Bg[(size_t)(k0 + kk) * ORD + col0 + n2];
        }
        __syncthreads();
        #pragma unroll
        for (int kk = 0; kk < 16; ++kk) {
            float a[4], b[4];
            #pragma unroll
            for (int i = 0; i < 4; ++i) a[i] = As[kk][ty * 4 + i];
            #pragma unroll
            for (int j = 0; j < 4; ++j) b[j] = Bs[kk][tx * 4 + j];
            #pragma unroll
            for (int i = 0; i < 4; ++i)
                #pragma unroll
                for (int j = 0; j < 4; ++j) acc[i][j] += a[i] * b[j];
        }
        __syncthreads();
    }
    #pragma unroll
    for (int i = 0; i < 4; ++i) {
        int row = row0 + ty * 4 + i;
        #pragma unroll
        for (int j = 0; j < 4; ++j) {
            int o = col0 + tx * 4 + j;
            Mq[(size_t)(q + 1) * (BD * ORD) + (size_t)row * ORD + o] =
                acc[i][j] + Lend[(size_t)q * (BD * ORD) + (size_t)row * ORD + o];
        }
    }
}

// ---- stage2+4 fused: mbuf[(bl,qC+c,d,o)] = L[q,c] + Mq[q] @ A^(c+1) ----
// Group of G batches: local rows r in [0, nrows), global bd = gbase + r.
__global__ __launch_bounds__(256) void k_stage24(const float* __restrict__ U2,
                                                 const float* __restrict__ Ptri,
                                                 const float* __restrict__ Mq,
                                                 const float* __restrict__ Apow,
                                                 float* __restrict__ mbuf,
                                                 int gbase, int nrows) {
    __shared__ float As[16][65];
    __shared__ float Bs[16][65];
    const int q    = blockIdx.z;
    const int row0 = blockIdx.y * 64;   // local row tile
    const int col0 = blockIdx.x * 64;   // over CH*ORD=16384
    const int tid  = threadIdx.x;
    const int tx = tid & 15, ty = tid >> 4;

    float acc[4][4] = {};

    // ---- part 1: L = U2-chunk (K=CH) x Ptri ----
    for (int k0 = 0; k0 < CH; k0 += 16) {
        for (int i = tid; i < 64 * 16; i += 256) {
            int m = i >> 4, kk = i & 15;
            As[kk][m] = U2[(size_t)(gbase + row0 + m) * T + q * CH + k0 + kk];
        }
        for (int i = tid; i < 16 * 64; i += 256) {
            int kk = i >> 6, n2 = i & 63;
            Bs[kk][n2] = Ptri[(size_t)(k0 + kk) * (CH * ORD) + col0 + n2];
        }
        __syncthreads();
        #pragma unroll
        for (int kk = 0; kk < 16; ++kk) {
            float a[4], b[4];
            #pragma unroll
            for (int i = 0; i < 4; ++i) a[i] = As[kk][ty * 4 + i];
            #pragma unroll
            for (int j = 0; j < 4; ++j) b[j] = Bs[kk][tx * 4 + j];
            #pragma unroll
            for (int i = 0; i < 4; ++i)
                #pragma unroll
                for (int j = 0; j < 4; ++j) acc[i][j] += a[i] * b[j];
        }
        __syncthreads();
    }

    // ---- part 2: + Mq[q] (K=ORD) x A^(c+1)  (skip q=0: M_0 = 0) ----
    if (q > 0) {
        const float* Ag = Mq + (size_t)q * (BD * ORD);
        for (int k0 = 0; k0 < ORD; k0 += 16) {
            for (int i = tid; i < 64 * 16; i += 256) {
                int m = i >> 4, kk = i & 15;
                As[kk][m] = Ag[(size_t)(gbase + row0 + m) * ORD + k0 + kk];
            }
            for (int i = tid; i < 16 * 64; i += 256) {
                int kk = i >> 6, n2 = i & 63;
                int col = col0 + n2;
                int c = col >> 8, o = col & 255;
                Bs[kk][n2] = Apow[(size_t)(c + 1) * OO + (size_t)(k0 + kk) * ORD + o];
            }
            __syncthreads();
            #pragma unroll
            for (int kk = 0; kk < 16; ++kk) {
                float a[4], b[4];
                #pragma unroll
                for (int i = 0; i < 4; ++i) a[i] = As[kk][ty * 4 + i];
                #pragma unroll
                for (int j = 0; j < 4; ++j) b[j] = Bs[kk][tx * 4 + j];
                #pragma unroll
                for (int i = 0; i < 4; ++i)
                    #pragma unroll
                    for (int j = 0; j < 4; ++j) acc[i][j] += a[i] * b[j];
            }
            __syncthreads();
        }
    }

    // ---- store (local batch layout), masked for partial groups ----
    #pragma unroll
    for (int i = 0; i < 4; ++i) {
        int r = row0 + ty * 4 + i;
        if (r >= nrows) continue;
        int bl = r >> 3, d = r & 7;
        int col = col0 + tx * 4;
        int c = col >> 8, o = col & 255;
        size_t addr = ((size_t)(bl * T + q * CH + c)) * DO + d * ORD + o;
        float4 v = make_float4(acc[i][0], acc[i][1], acc[i][2], acc[i][3]);
        *(float4*)&mbuf[addr] = v;
    }
}

// ---------------- stage5: out = tanh(mbuf @ Wh + bh) ----------------
__global__ __launch_bounds__(256) void k_stage5(const float* __restrict__ mbuf,
                                                const float* __restrict__ Wh,
                                                const float* __restrict__ bh,
                                                float* __restrict__ out) {
    __shared__ float As[16][132];
    __shared__ float Bs[16][132];
    const int row0 = blockIdx.y * 128;   // over G*1024 local rows
    const int col0 = blockIdx.x * 128;   // over 512
    const int tid  = threadIdx.x;
    const int tx = tid & 15, ty = tid >> 4;

    float acc[8][8] = {};
    for (int k0 = 0; k0 < DO; k0 += 16) {
        for (int i = tid; i < 128 * 16; i += 256) {
            int m = i >> 4, kk = i & 15;
            As[kk][m] = mbuf[(size_t)(row0 + m) * DO + k0 + kk];
        }
        for (int i = tid; i < 16 * 128; i += 256) {
            int kk = i >> 7, n2 = i & 127;
            Bs[kk][n2] = Wh[(size_t)(k0 + kk) * HID + col0 + n2];
        }
        __syncthreads();
        #pragma unroll
        for (int kk = 0; kk < 16; ++kk) {
            float a[8], b[8];
            #pragma unroll
            for (int i = 0; i < 8; ++i) a[i] = As[kk][ty * 4 + ((i >= 4) ? 64 : 0) + (i & 3)];
            #pragma unroll
            for (int j = 0; j < 8; ++j) b[j] = Bs[kk][tx * 4 + ((j >= 4) ? 64 : 0) + (j & 3)];
            #pragma unroll
            for (int i = 0; i < 8; ++i)
                #pragma unroll
                for (int j = 0; j < 8; ++j) acc[i][j] += a[i] * b[j];
        }
        __syncthreads();
    }
    #pragma unroll
    for (int i = 0; i < 8; ++i) {
        int row = row0 + ty * 4 + ((i >= 4) ? 64 : 0) + (i & 3);
        #pragma unroll
        for (int jh = 0; jh < 2; ++jh) {
            int col = col0 + tx * 4 + jh * 64;
            float4 v;
            v.x = tanhf(acc[i][jh * 4 + 0] + bh[col + 0]);
            v.y = tanhf(acc[i][jh * 4 + 1] + bh[col + 1]);
            v.z = tanhf(acc[i][jh * 4 + 2] + bh[col + 2]);
            v.w = tanhf(acc[i][jh * 4 + 3] + bh[col + 3]);
            *(float4*)&out[(size_t)row * HID + col] = v;
        }
    }
}

// ---------------- launch ----------------
extern "C" void kernel_launch(void* const* d_in, const int* in_sizes, int n_in,
                              void* d_out, int out_size, void* d_ws, size_t ws_size,
                              hipStream_t stream) {
    const float* x    = (const float*)d_in[0];
    const float* kern = (const float*)d_in[1];
    const float* Wh   = (const float*)d_in[2];
    const float* bh   = (const float*)d_in[3];
    const float* A    = (const float*)d_in[4];
    const float* Brow = (const float*)d_in[5];
    float* out = (float*)d_out;

    float* ws   = (float*)d_ws;
    float* U2   = ws + OFF_U2;
    float* P    = ws + OFF_P;
    float* Ptri = ws + OFF_PTRI;
    float* Apow = ws + OFF_APOW;
    float* Mq   = ws + OFF_MQ;
    float* Lend = ws + OFF_LEND;
    float* mbuf = ws + OFF_MBUF;

    // choose largest batch group that fits the workspace
    const size_t availF = ws_size / sizeof(float);
    int G = 1;
    for (int g = 32; g >= 1; g >>= 1) {
        if (OFF_MBUF + (size_t)g * T * DO <= availF) { G = g; break; }
    }
    const int ngroups = BSZ / G;

    // U projection (all batches)
    k_u<<<dim3(BSZ * (T / 32)), 256, 0, stream>>>(x, kern, U2);

    // A powers 1..64 by doubling
    k_copyA<<<dim3(OO / 256), 256, 0, stream>>>(A, Apow);
    for (int n = 1; n < CH; n <<= 1)
        k_pow<<<dim3(4, 4, n), 256, 0, stream>>>(Apow, n);

    // P rows, triangular expansion, chunk-end partials
    k_p<<<dim3(CH), 256, 0, stream>>>(Brow, Apow, P);
    k_ptri<<<dim3((CH * CH * ORD) / 256), 256, 0, stream>>>(P, Ptri);
    k_lend<<<dim3(ORD / 64, BD / 64, NQ), 256, 0, stream>>>(U2, P, Lend);

    // M_0 = 0, then sequential chunk-boundary chain
    k_zero<<<dim3((BD * ORD) / 256), 256, 0, stream>>>(Mq, BD * ORD);
    for (int q = 0; q < NQ - 1; ++q)
        k_stage3<<<dim3(ORD / 64, BD / 64), 256, 0, stream>>>(Mq, Apow, Lend, q);

    // per batch-group: fused m materialization + output GEMM
    for (int g = 0; g < ngroups; ++g) {
        const int gbase = g * G * MD;            // global bd row base
        const int nrows = G * MD;                // rows in this group
        const int gy    = (nrows + 63) / 64;
        k_stage24<<<dim3((CH * ORD) / 64, gy, NQ), 256, 0, stream>>>(
            U2, Ptri, Mq, Apow, mbuf, gbase, nrows);
        k_stage5<<<dim3(HID / 128, (G * T) / 128), 256, 0, stream>>>(
            mbuf, Wh, bh, out + (size_t)g * G * T * HID);
    }
}

// Round 3
// 1006.434 us; speedup vs baseline: 2.7408x; 2.7408x over previous
//
#include <hip/hip_runtime.h>
#include <cstdint>
#include <cstddef>

// ---------------- problem constants ----------------
constexpr int BSZ = 32;
constexpr int T   = 1024;
constexpr int ID  = 256;
constexpr int MD  = 8;
constexpr int ORD = 256;
constexpr int HID = 512;
constexpr int BD  = BSZ * MD;   // 256
constexpr int CH  = 64;
constexpr int NQ  = T / CH;     // 16
constexpr int DO  = MD * ORD;   // 2048
constexpr int OO  = ORD * ORD;  // 65536
constexpr int KTOT24 = CH + ORD; // 320

typedef unsigned short ushort_t;
typedef __attribute__((ext_vector_type(8))) short bf16x8;
typedef __attribute__((ext_vector_type(8))) unsigned short us8;
typedef __attribute__((ext_vector_type(4))) float f32x4;

__device__ inline ushort_t f2bf(float f) {
    union { float f; uint32_t u; } v; v.f = f;
    uint32_t r = v.u + 0x7fffu + ((v.u >> 16) & 1u);
    return (ushort_t)(r >> 16);
}

// ---------------- workspace layout (bytes) ----------------
constexpr size_t AL = 256;
constexpr size_t alup(size_t x) { return (x + AL - 1) & ~(AL - 1); }
constexpr size_t OFF_U2   = 0;                                          // f32 BD*T
constexpr size_t OFF_P    = alup(OFF_U2   + (size_t)BD * T * 4);        // f32 CH*ORD
constexpr size_t OFF_APOW = alup(OFF_P    + (size_t)CH * ORD * 4);      // f32 (CH+1)*OO
constexpr size_t OFF_MQ   = alup(OFF_APOW + (size_t)(CH + 1) * OO * 4); // f32 NQ*BD*ORD
constexpr size_t OFF_LEND = alup(OFF_MQ   + (size_t)NQ * BD * ORD * 4); // f32 NQ*BD*ORD
constexpr size_t OFF_U2B  = alup(OFF_LEND + (size_t)NQ * BD * ORD * 4); // bf16 BD*T
constexpr size_t OFF_PTRB = alup(OFF_U2B  + (size_t)BD * T * 2);        // bf16 (CH*ORD)*CH
constexpr size_t OFF_APB  = alup(OFF_PTRB + (size_t)CH * ORD * CH * 2); // bf16 (CH*ORD)*ORD
constexpr size_t OFF_WHBT = alup(OFF_APB  + (size_t)CH * ORD * ORD * 2);// bf16 HID*DO
constexpr size_t OFF_MQB  = alup(OFF_WHBT + (size_t)HID * DO * 2);      // bf16 NQ*BD*ORD
constexpr size_t OFF_MBUF = alup(OFF_MQB  + (size_t)NQ * BD * ORD * 2); // bf16 G*T*DO

// ---------------- zero a float range ----------------
__global__ __launch_bounds__(256) void k_zero(float* __restrict__ p, int n) {
    int i = blockIdx.x * 256 + threadIdx.x;
    if (i < n) p[i] = 0.f;
}

// ---------------- U2[bd][t] (f32 + bf16) ----------------
__global__ __launch_bounds__(256) void k_u(const float* __restrict__ x,
                                           const float* __restrict__ kern,
                                           float* __restrict__ U2,
                                           ushort_t* __restrict__ U2b) {
    __shared__ float xs[32][ID + 1];
    __shared__ float ks[ID][MD];
    const int blk = blockIdx.x;
    const int b   = blk / (T / 32);
    const int t0  = (blk % (T / 32)) * 32;
    const int tid = threadIdx.x;

    for (int i = tid; i < ID * MD; i += 256) ks[i / MD][i % MD] = kern[i];
    const float* xp = x + ((size_t)b * T + t0) * ID;
    for (int i = tid; i < 32 * ID; i += 256) xs[i >> 8][i & 255] = xp[i];
    __syncthreads();

    const int d  = tid / 32;
    const int tl = tid % 32;
    float acc = 0.f;
    #pragma unroll 8
    for (int i = 0; i < ID; ++i) acc += xs[tl][i] * ks[i][d];
    size_t idx = ((size_t)b * MD + d) * T + t0 + tl;
    U2[idx]  = acc;
    U2b[idx] = f2bf(acc);
}

// ---------------- copy A -> Apow[1] ----------------
__global__ __launch_bounds__(256) void k_copyA(const float* __restrict__ A,
                                               float* __restrict__ Apow) {
    int idx = blockIdx.x * 256 + threadIdx.x;
    Apow[OO + idx] = A[idx];
}

// ---------------- doubling: Apow[n+z+1] = Apow[z+1] @ Apow[n] ----------------
__global__ __launch_bounds__(256) void k_pow(float* __restrict__ Apow, int n) {
    __shared__ float As[16][65];
    __shared__ float Bs[16][65];
    const int z    = blockIdx.z;
    const int row0 = blockIdx.y * 64;
    const int col0 = blockIdx.x * 64;
    const int tid  = threadIdx.x;
    const int tx = tid & 15, ty = tid >> 4;
    const float* Ag = Apow + (size_t)(z + 1) * OO;
    const float* Bg = Apow + (size_t)n * OO;
    float*       Cg = Apow + (size_t)(n + z + 1) * OO;

    float acc[4][4] = {};
    for (int k0 = 0; k0 < ORD; k0 += 16) {
        for (int i = tid; i < 64 * 16; i += 256) {
            int m = i >> 4, kk = i & 15;
            As[kk][m] = Ag[(size_t)(row0 + m) * ORD + k0 + kk];
        }
        for (int i = tid; i < 16 * 64; i += 256) {
            int kk = i >> 6, n2 = i & 63;
            Bs[kk][n2] = Bg[(size_t)(k0 + kk) * ORD + col0 + n2];
        }
        __syncthreads();
        #pragma unroll
        for (int kk = 0; kk < 16; ++kk) {
            float a[4], b[4];
            #pragma unroll
            for (int i = 0; i < 4; ++i) a[i] = As[kk][ty * 4 + i];
            #pragma unroll
            for (int j = 0; j < 4; ++j) b[j] = Bs[kk][tx * 4 + j];
            #pragma unroll
            for (int i = 0; i < 4; ++i)
                #pragma unroll
                for (int j = 0; j < 4; ++j) acc[i][j] += a[i] * b[j];
        }
        __syncthreads();
    }
    #pragma unroll
    for (int i = 0; i < 4; ++i) {
        float4 v = make_float4(acc[i][0], acc[i][1], acc[i][2], acc[i][3]);
        *(float4*)&Cg[(size_t)(row0 + ty * 4 + i) * ORD + col0 + tx * 4] = v;
    }
}

// ---------------- P[k] = Brow @ A^k ----------------
__global__ __launch_bounds__(256) void k_p(const float* __restrict__ Brow,
                                           const float* __restrict__ Apow,
                                           float* __restrict__ P) {
    __shared__ float br[ORD];
    const int k = blockIdx.x;
    const int o = threadIdx.x;
    br[o] = Brow[o];
    __syncthreads();
    if (k == 0) { P[o] = br[o]; return; }
    const float* M = Apow + (size_t)k * OO;
    float acc = 0.f;
    #pragma unroll 4
    for (int op = 0; op < ORD; ++op) acc += br[op] * M[(size_t)op * ORD + o];
    P[(size_t)k * ORD + o] = acc;
}

// ---------------- Ptrib[col=(c,o)][j] = bf16(P[c-j][o]) or 0 ----------------
__global__ __launch_bounds__(256) void k_ptrib(const float* __restrict__ P,
                                               ushort_t* __restrict__ Ptrib) {
    int idx = blockIdx.x * 256 + threadIdx.x;   // (CH*ORD)*CH
    int col = idx >> 6, j = idx & (CH - 1);
    int c = col >> 8, o = col & 255;
    float v = (j <= c) ? P[(size_t)(c - j) * ORD + o] : 0.f;
    Ptrib[idx] = f2bf(v);
}

// ---------------- Apb[col=(c,o)][op] = bf16(A^{c+1}[op][o]) ----------------
__global__ __launch_bounds__(256) void k_apb(const float* __restrict__ Apow,
                                             ushort_t* __restrict__ Apb) {
    int idx = blockIdx.x * 256 + threadIdx.x;   // (CH*ORD)*ORD
    int col = idx >> 8, op = idx & 255;
    int c = col >> 8, o = col & 255;
    Apb[idx] = f2bf(Apow[(size_t)(c + 1) * OO + (size_t)op * ORD + o]);
}

// ---------------- Whbt[col][k] = bf16(Wh[k][col]) ----------------
__global__ __launch_bounds__(256) void k_whbt(const float* __restrict__ Wh,
                                              ushort_t* __restrict__ Whbt) {
    int idx = blockIdx.x * 256 + threadIdx.x;   // HID*DO
    int col = idx >> 11, k = idx & (DO - 1);
    Whbt[idx] = f2bf(Wh[(size_t)k * HID + col]);
}

// ---------------- Mqb = bf16(Mq) ----------------
__global__ __launch_bounds__(256) void k_mqb(const float* __restrict__ Mq,
                                             ushort_t* __restrict__ Mqb) {
    int idx = blockIdx.x * 256 + threadIdx.x;   // NQ*BD*ORD
    Mqb[idx] = f2bf(Mq[idx]);
}

// ---------------- Lend[q,bd,o] = sum_j U2[bd,qC+j] * P[CH-1-j,o]  (f32) ----
__global__ __launch_bounds__(256) void k_lend(const float* __restrict__ U2,
                                              const float* __restrict__ P,
                                              float* __restrict__ Lend) {
    __shared__ float As[16][65];
    __shared__ float Bs[16][65];
    const int q    = blockIdx.z;
    const int row0 = blockIdx.y * 64;
    const int col0 = blockIdx.x * 64;
    const int tid  = threadIdx.x;
    const int tx = tid & 15, ty = tid >> 4;

    float acc[4][4] = {};
    for (int k0 = 0; k0 < CH; k0 += 16) {
        for (int i = tid; i < 64 * 16; i += 256) {
            int m = i >> 4, kk = i & 15;
            As[kk][m] = U2[(size_t)(row0 + m) * T + q * CH + k0 + kk];
        }
        for (int i = tid; i < 16 * 64; i += 256) {
            int kk = i >> 6, n2 = i & 63;
            Bs[kk][n2] = P[(size_t)(CH - 1 - (k0 + kk)) * ORD + col0 + n2];
        }
        __syncthreads();
        #pragma unroll
        for (int kk = 0; kk < 16; ++kk) {
            float a[4], b[4];
            #pragma unroll
            for (int i = 0; i < 4; ++i) a[i] = As[kk][ty * 4 + i];
            #pragma unroll
            for (int j = 0; j < 4; ++j) b[j] = Bs[kk][tx * 4 + j];
            #pragma unroll
            for (int i = 0; i < 4; ++i)
                #pragma unroll
                for (int j = 0; j < 4; ++j) acc[i][j] += a[i] * b[j];
        }
        __syncthreads();
    }
    #pragma unroll
    for (int i = 0; i < 4; ++i) {
        float4 v = make_float4(acc[i][0], acc[i][1], acc[i][2], acc[i][3]);
        *(float4*)&Lend[(size_t)q * (BD * ORD) +
                        (size_t)(row0 + ty * 4 + i) * ORD + col0 + tx * 4] = v;
    }
}

// ---------------- stage3: Mq[q+1] = Mq[q] @ A^CH + Lend[q]  (f32) ----------
__global__ __launch_bounds__(256) void k_stage3(float* __restrict__ Mq,
                                                const float* __restrict__ Apow,
                                                const float* __restrict__ Lend,
                                                int q) {
    __shared__ float As[16][65];
    __shared__ float Bs[16][65];
    const int row0 = blockIdx.y * 64;
    const int col0 = blockIdx.x * 64;
    const int tid  = threadIdx.x;
    const int tx = tid & 15, ty = tid >> 4;
    const float* Ag = Mq + (size_t)q * (BD * ORD);
    const float* Bg = Apow + (size_t)CH * OO;

    float acc[4][4] = {};
    for (int k0 = 0; k0 < ORD; k0 += 16) {
        for (int i = tid; i < 64 * 16; i += 256) {
            int m = i >> 4, kk = i & 15;
            As[kk][m] = Ag[(size_t)(row0 + m) * ORD + k0 + kk];
        }
        for (int i = tid; i < 16 * 64; i += 256) {
            int kk = i >> 6, n2 = i & 63;
            Bs[kk][n2] = Bg[(size_t)(k0 + kk) * ORD + col0 + n2];
        }
        __syncthreads();
        #pragma unroll
        for (int kk = 0; kk < 16; ++kk) {
            float a[4], b[4];
            #pragma unroll
            for (int i = 0; i < 4; ++i) a[i] = As[kk][ty * 4 + i];
            #pragma unroll
            for (int j = 0; j < 4; ++j) b[j] = Bs[kk][tx * 4 + j];
            #pragma unroll
            for (int i = 0; i < 4; ++i)
                #pragma unroll
                for (int j = 0; j < 4; ++j) acc[i][j] += a[i] * b[j];
        }
        __syncthreads();
    }
    #pragma unroll
    for (int i = 0; i < 4; ++i) {
        int row = row0 + ty * 4 + i;
        #pragma unroll
        for (int j = 0; j < 4; ++j) {
            int o = col0 + tx * 4 + j;
            Mq[(size_t)(q + 1) * (BD * ORD) + (size_t)row * ORD + o] =
                acc[i][j] + Lend[(size_t)q * (BD * ORD) + (size_t)row * ORD + o];
        }
    }
}

// ====== MFMA GEMM 1: mbuf = [U2chunk | Mq] @ [Ptrib ; Apb]  (K=320) ======
// grid: x = 128 (cols/128 over CH*ORD), y = ceil(nrows/128), z = q
__global__ __launch_bounds__(256) void k_gemm24(const ushort_t* __restrict__ U2b,
                                                const ushort_t* __restrict__ Mqb,
                                                const ushort_t* __restrict__ Ptrib,
                                                const ushort_t* __restrict__ Apb,
                                                ushort_t* __restrict__ mbuf,
                                                int gbase, int nrows) {
    __shared__ ushort_t Als[128][40];
    __shared__ ushort_t Bls[128][40];
    const int q       = blockIdx.z;
    const int rowbase = blockIdx.y * 128;
    const int colbase = blockIdx.x * 128;
    const int tid  = threadIdx.x;
    const int lane = tid & 63;
    const int wid  = tid >> 6;
    const int wr = wid >> 1, wc = wid & 1;
    const int lr = lane & 15, lk = (lane >> 4) * 8;

    f32x4 acc[4][4];
    #pragma unroll
    for (int m = 0; m < 4; ++m)
        #pragma unroll
        for (int n = 0; n < 4; ++n) acc[m][n] = 0.f;

    for (int s = 0; s < KTOT24 / 32; ++s) {
        const int k0 = s * 32;
        #pragma unroll
        for (int i = 0; i < 2; ++i) {
            int f = tid + i * 256;
            int row = f >> 2, kv = (f & 3) * 8;
            int r2 = rowbase + row; if (r2 >= nrows) r2 = 0;
            us8 va, vb;
            if (k0 < CH) {
                va = *(const us8*)&U2b[(size_t)(gbase + r2) * T + q * CH + k0 + kv];
                vb = *(const us8*)&Ptrib[(size_t)(colbase + row) * CH + k0 + kv];
            } else {
                va = *(const us8*)&Mqb[((size_t)q * BD + gbase + r2) * ORD + (k0 - CH) + kv];
                vb = *(const us8*)&Apb[(size_t)(colbase + row) * ORD + (k0 - CH) + kv];
            }
            *(us8*)&Als[row][kv] = va;
            *(us8*)&Bls[row][kv] = vb;
        }
        __syncthreads();
        bf16x8 af[4], bfv[4];
        #pragma unroll
        for (int m = 0; m < 4; ++m) af[m]  = *(const bf16x8*)&Als[wr * 64 + m * 16 + lr][lk];
        #pragma unroll
        for (int n = 0; n < 4; ++n) bfv[n] = *(const bf16x8*)&Bls[wc * 64 + n * 16 + lr][lk];
        #pragma unroll
        for (int m = 0; m < 4; ++m)
            #pragma unroll
            for (int n = 0; n < 4; ++n)
                acc[m][n] = __builtin_amdgcn_mfma_f32_16x16x32_bf16(af[m], bfv[n], acc[m][n], 0, 0, 0);
        __syncthreads();
    }

    #pragma unroll
    for (int m = 0; m < 4; ++m) {
        #pragma unroll
        for (int n = 0; n < 4; ++n) {
            int colv = colbase + wc * 64 + n * 16 + lr;
            int c = colv >> 8, o = colv & 255;
            #pragma unroll
            for (int r = 0; r < 4; ++r) {
                int grow = rowbase + wr * 64 + m * 16 + ((lane >> 4) << 2) + r;
                if (grow < nrows) {
                    int bl = grow >> 3, d = grow & 7;
                    mbuf[((size_t)(bl * T + q * CH + c)) * DO + (d << 8) + o] =
                        f2bf(acc[m][n][r]);
                }
            }
        }
    }
}

// ====== MFMA GEMM 2: out = tanh(mbuf @ Wh + bh)  (K=2048) ======
// grid: x = HID/128 = 4, y = G*8
__global__ __launch_bounds__(256) void k_gemm5(const ushort_t* __restrict__ mbuf,
                                               const ushort_t* __restrict__ Whbt,
                                               const float* __restrict__ bh,
                                               float* __restrict__ out) {
    __shared__ ushort_t Als[128][40];
    __shared__ ushort_t Bls[128][40];
    const int rowbase = blockIdx.y * 128;
    const int colbase = blockIdx.x * 128;
    const int tid  = threadIdx.x;
    const int lane = tid & 63;
    const int wid  = tid >> 6;
    const int wr = wid >> 1, wc = wid & 1;
    const int lr = lane & 15, lk = (lane >> 4) * 8;

    f32x4 acc[4][4];
    #pragma unroll
    for (int m = 0; m < 4; ++m)
        #pragma unroll
        for (int n = 0; n < 4; ++n) acc[m][n] = 0.f;

    for (int s = 0; s < DO / 32; ++s) {
        const int k0 = s * 32;
        #pragma unroll
        for (int i = 0; i < 2; ++i) {
            int f = tid + i * 256;
            int row = f >> 2, kv = (f & 3) * 8;
            *(us8*)&Als[row][kv] =
                *(const us8*)&mbuf[(size_t)(rowbase + row) * DO + k0 + kv];
            *(us8*)&Bls[row][kv] =
                *(const us8*)&Whbt[(size_t)(colbase + row) * DO + k0 + kv];
        }
        __syncthreads();
        bf16x8 af[4], bfv[4];
        #pragma unroll
        for (int m = 0; m < 4; ++m) af[m]  = *(const bf16x8*)&Als[wr * 64 + m * 16 + lr][lk];
        #pragma unroll
        for (int n = 0; n < 4; ++n) bfv[n] = *(const bf16x8*)&Bls[wc * 64 + n * 16 + lr][lk];
        #pragma unroll
        for (int m = 0; m < 4; ++m)
            #pragma unroll
            for (int n = 0; n < 4; ++n)
                acc[m][n] = __builtin_amdgcn_mfma_f32_16x16x32_bf16(af[m], bfv[n], acc[m][n], 0, 0, 0);
        __syncthreads();
    }

    #pragma unroll
    for (int m = 0; m < 4; ++m) {
        #pragma unroll
        for (int n = 0; n < 4; ++n) {
            int col = colbase + wc * 64 + n * 16 + lr;
            float bias = bh[col];
            #pragma unroll
            for (int r = 0; r < 4; ++r) {
                int grow = rowbase + wr * 64 + m * 16 + ((lane >> 4) << 2) + r;
                out[(size_t)grow * HID + col] = tanhf(acc[m][n][r] + bias);
            }
        }
    }
}

// ---------------- launch ----------------
extern "C" void kernel_launch(void* const* d_in, const int* in_sizes, int n_in,
                              void* d_out, int out_size, void* d_ws, size_t ws_size,
                              hipStream_t stream) {
    const float* x    = (const float*)d_in[0];
    const float* kern = (const float*)d_in[1];
    const float* Wh   = (const float*)d_in[2];
    const float* bh   = (const float*)d_in[3];
    const float* A    = (const float*)d_in[4];
    const float* Brow = (const float*)d_in[5];
    float* out = (float*)d_out;

    char* base = (char*)d_ws;
    float*    U2    = (float*)(base + OFF_U2);
    float*    P     = (float*)(base + OFF_P);
    float*    Apow  = (float*)(base + OFF_APOW);
    float*    Mq    = (float*)(base + OFF_MQ);
    float*    Lend  = (float*)(base + OFF_LEND);
    ushort_t* U2b   = (ushort_t*)(base + OFF_U2B);
    ushort_t* Ptrib = (ushort_t*)(base + OFF_PTRB);
    ushort_t* Apb   = (ushort_t*)(base + OFF_APB);
    ushort_t* Whbt  = (ushort_t*)(base + OFF_WHBT);
    ushort_t* Mqb   = (ushort_t*)(base + OFF_MQB);
    ushort_t* mbuf  = (ushort_t*)(base + OFF_MBUF);

    // choose largest batch group whose bf16 mbuf fits
    int G = 1;
    for (int g = 32; g >= 1; g >>= 1) {
        if (OFF_MBUF + (size_t)g * T * DO * 2 <= ws_size) { G = g; break; }
    }
    const int ngroups = BSZ / G;

    // U projection (f32 + bf16)
    k_u<<<dim3(BSZ * (T / 32)), 256, 0, stream>>>(x, kern, U2, U2b);

    // A powers 1..64 by doubling (f32)
    k_copyA<<<dim3(OO / 256), 256, 0, stream>>>(A, Apow);
    for (int n = 1; n < CH; n <<= 1)
        k_pow<<<dim3(4, 4, n), 256, 0, stream>>>(Apow, n);

    // P rows (f32), bf16 operand prep
    k_p<<<dim3(CH), 256, 0, stream>>>(Brow, Apow, P);
    k_ptrib<<<dim3((CH * ORD * CH) / 256), 256, 0, stream>>>(P, Ptrib);
    k_apb<<<dim3((CH * ORD * ORD) / 256), 256, 0, stream>>>(Apow, Apb);
    k_whbt<<<dim3((HID * DO) / 256), 256, 0, stream>>>(Wh, Whbt);

    // chunk-end partials + boundary chain (f32)
    k_lend<<<dim3(ORD / 64, BD / 64, NQ), 256, 0, stream>>>(U2, P, Lend);
    k_zero<<<dim3((BD * ORD) / 256), 256, 0, stream>>>(Mq, BD * ORD);
    for (int q = 0; q < NQ - 1; ++q)
        k_stage3<<<dim3(ORD / 64, BD / 64), 256, 0, stream>>>(Mq, Apow, Lend, q);
    k_mqb<<<dim3((NQ * BD * ORD) / 256), 256, 0, stream>>>(Mq, Mqb);

    // per batch-group: MFMA m-materialization + MFMA output GEMM
    for (int g = 0; g < ngroups; ++g) {
        const int gbase = g * G * MD;
        const int nrows = G * MD;
        const int gy    = (nrows + 127) / 128;
        k_gemm24<<<dim3((CH * ORD) / 128, gy, NQ), 256, 0, stream>>>(
            U2b, Mqb, Ptrib, Apb, mbuf, gbase, nrows);
        k_gemm5<<<dim3(HID / 128, (G * T) / 128), 256, 0, stream>>>(
            mbuf, Whbt, bh, out + (size_t)g * G * T * HID);
    }
}

// Round 4
// 727.431 us; speedup vs baseline: 3.7921x; 1.3835x over previous
//
#include <hip/hip_runtime.h>
#include <cstdint>
#include <cstddef>

// ---------------- problem constants ----------------
constexpr int BSZ = 32;
constexpr int T   = 1024;
constexpr int ID  = 256;
constexpr int MD  = 8;
constexpr int ORD = 256;
constexpr int HID = 512;
constexpr int BD  = BSZ * MD;   // 256
constexpr int CH  = 64;
constexpr int NQ  = T / CH;     // 16
constexpr int DO  = MD * ORD;   // 2048
constexpr int OO  = ORD * ORD;  // 65536
constexpr int KTOT24 = CH + ORD; // 320

typedef unsigned short ushort_t;
typedef __attribute__((ext_vector_type(8))) short bf16x8;
typedef __attribute__((ext_vector_type(8))) unsigned short us8;
typedef __attribute__((ext_vector_type(4))) float f32x4;

__device__ inline ushort_t f2bf(float f) {
    union { float f; uint32_t u; } v; v.f = f;
    uint32_t r = v.u + 0x7fffu + ((v.u >> 16) & 1u);
    return (ushort_t)(r >> 16);
}

// ---------------- workspace layout (bytes) — identical footprint to R3 ----
constexpr size_t AL = 256;
constexpr size_t alup(size_t x) { return (x + AL - 1) & ~(AL - 1); }
constexpr size_t OFF_U2   = 0;                                          // f32 BD*T (dead after k_lend; reused for A256/A512)
constexpr size_t OFF_P    = alup(OFF_U2   + (size_t)BD * T * 4);        // f32 CH*ORD
constexpr size_t OFF_APOW = alup(OFF_P    + (size_t)CH * ORD * 4);      // f32 (CH+1)*OO (slot 0 reused for A128)
constexpr size_t OFF_MQ   = alup(OFF_APOW + (size_t)(CH + 1) * OO * 4); // f32 NQ*BD*ORD (scan buffer A)
constexpr size_t OFF_LEND = alup(OFF_MQ   + (size_t)NQ * BD * ORD * 4); // f32 NQ*BD*ORD (Lend, then scan buffer B)
constexpr size_t OFF_U2B  = alup(OFF_LEND + (size_t)NQ * BD * ORD * 4); // bf16 BD*T
constexpr size_t OFF_PTRB = alup(OFF_U2B  + (size_t)BD * T * 2);        // bf16 (CH*ORD)*CH
constexpr size_t OFF_APB  = alup(OFF_PTRB + (size_t)CH * ORD * CH * 2); // bf16 (CH*ORD)*ORD
constexpr size_t OFF_WHBT = alup(OFF_APB  + (size_t)CH * ORD * ORD * 2);// bf16 HID*DO
constexpr size_t OFF_MQB  = alup(OFF_WHBT + (size_t)HID * DO * 2);      // bf16 NQ*BD*ORD
constexpr size_t OFF_MBUF = alup(OFF_MQB  + (size_t)NQ * BD * ORD * 2); // bf16 G*T*DO

// ---------------- U2[bd][t] (f32 + bf16) ----------------
__global__ __launch_bounds__(256) void k_u(const float* __restrict__ x,
                                           const float* __restrict__ kern,
                                           float* __restrict__ U2,
                                           ushort_t* __restrict__ U2b) {
    __shared__ float xs[32][ID + 1];
    __shared__ float ks[ID][MD];
    const int blk = blockIdx.x;
    const int b   = blk / (T / 32);
    const int t0  = (blk % (T / 32)) * 32;
    const int tid = threadIdx.x;

    for (int i = tid; i < ID * MD; i += 256) ks[i / MD][i % MD] = kern[i];
    const float* xp = x + ((size_t)b * T + t0) * ID;
    for (int i = tid; i < 32 * ID; i += 256) xs[i >> 8][i & 255] = xp[i];
    __syncthreads();

    const int d  = tid / 32;
    const int tl = tid % 32;
    float acc = 0.f;
    #pragma unroll 8
    for (int i = 0; i < ID; ++i) acc += xs[tl][i] * ks[i][d];
    size_t idx = ((size_t)b * MD + d) * T + t0 + tl;
    U2[idx]  = acc;
    U2b[idx] = f2bf(acc);
}

// ---------------- copy A -> Apow[1] ----------------
__global__ __launch_bounds__(256) void k_copyA(const float* __restrict__ A,
                                               float* __restrict__ Apow) {
    int idx = blockIdx.x * 256 + threadIdx.x;
    Apow[OO + idx] = A[idx];
}

// ---------------- doubling: Apow[n+z+1] = Apow[z+1] @ Apow[n] ----------------
__global__ __launch_bounds__(256) void k_pow(float* __restrict__ Apow, int n) {
    __shared__ float As[16][65];
    __shared__ float Bs[16][65];
    const int z    = blockIdx.z;
    const int row0 = blockIdx.y * 64;
    const int col0 = blockIdx.x * 64;
    const int tid  = threadIdx.x;
    const int tx = tid & 15, ty = tid >> 4;
    const float* Ag = Apow + (size_t)(z + 1) * OO;
    const float* Bg = Apow + (size_t)n * OO;
    float*       Cg = Apow + (size_t)(n + z + 1) * OO;

    float acc[4][4] = {};
    for (int k0 = 0; k0 < ORD; k0 += 16) {
        for (int i = tid; i < 64 * 16; i += 256) {
            int m = i >> 4, kk = i & 15;
            As[kk][m] = Ag[(size_t)(row0 + m) * ORD + k0 + kk];
        }
        for (int i = tid; i < 16 * 64; i += 256) {
            int kk = i >> 6, n2 = i & 63;
            Bs[kk][n2] = Bg[(size_t)(k0 + kk) * ORD + col0 + n2];
        }
        __syncthreads();
        #pragma unroll
        for (int kk = 0; kk < 16; ++kk) {
            float a[4], b[4];
            #pragma unroll
            for (int i = 0; i < 4; ++i) a[i] = As[kk][ty * 4 + i];
            #pragma unroll
            for (int j = 0; j < 4; ++j) b[j] = Bs[kk][tx * 4 + j];
            #pragma unroll
            for (int i = 0; i < 4; ++i)
                #pragma unroll
                for (int j = 0; j < 4; ++j) acc[i][j] += a[i] * b[j];
        }
        __syncthreads();
    }
    #pragma unroll
    for (int i = 0; i < 4; ++i) {
        float4 v = make_float4(acc[i][0], acc[i][1], acc[i][2], acc[i][3]);
        *(float4*)&Cg[(size_t)(row0 + ty * 4 + i) * ORD + col0 + tx * 4] = v;
    }
}

// ---------------- generic 256x256 f32 matmul: C = A @ B ----------------
__global__ __launch_bounds__(256) void k_sq(const float* __restrict__ Ag,
                                            const float* __restrict__ Bg,
                                            float* __restrict__ Cg) {
    __shared__ float As[16][65];
    __shared__ float Bs[16][65];
    const int row0 = blockIdx.y * 64;
    const int col0 = blockIdx.x * 64;
    const int tid  = threadIdx.x;
    const int tx = tid & 15, ty = tid >> 4;

    float acc[4][4] = {};
    for (int k0 = 0; k0 < ORD; k0 += 16) {
        for (int i = tid; i < 64 * 16; i += 256) {
            int m = i >> 4, kk = i & 15;
            As[kk][m] = Ag[(size_t)(row0 + m) * ORD + k0 + kk];
        }
        for (int i = tid; i < 16 * 64; i += 256) {
            int kk = i >> 6, n2 = i & 63;
            Bs[kk][n2] = Bg[(size_t)(k0 + kk) * ORD + col0 + n2];
        }
        __syncthreads();
        #pragma unroll
        for (int kk = 0; kk < 16; ++kk) {
            float a[4], b[4];
            #pragma unroll
            for (int i = 0; i < 4; ++i) a[i] = As[kk][ty * 4 + i];
            #pragma unroll
            for (int j = 0; j < 4; ++j) b[j] = Bs[kk][tx * 4 + j];
            #pragma unroll
            for (int i = 0; i < 4; ++i)
                #pragma unroll
                for (int j = 0; j < 4; ++j) acc[i][j] += a[i] * b[j];
        }
        __syncthreads();
    }
    #pragma unroll
    for (int i = 0; i < 4; ++i) {
        float4 v = make_float4(acc[i][0], acc[i][1], acc[i][2], acc[i][3]);
        *(float4*)&Cg[(size_t)(row0 + ty * 4 + i) * ORD + col0 + tx * 4] = v;
    }
}

// ---------------- P[k] = Brow @ A^k ----------------
__global__ __launch_bounds__(256) void k_p(const float* __restrict__ Brow,
                                           const float* __restrict__ Apow,
                                           float* __restrict__ P) {
    __shared__ float br[ORD];
    const int k = blockIdx.x;
    const int o = threadIdx.x;
    br[o] = Brow[o];
    __syncthreads();
    if (k == 0) { P[o] = br[o]; return; }
    const float* M = Apow + (size_t)k * OO;
    float acc = 0.f;
    #pragma unroll 4
    for (int op = 0; op < ORD; ++op) acc += br[op] * M[(size_t)op * ORD + o];
    P[(size_t)k * ORD + o] = acc;
}

// ---------------- Ptrib[col=(c,o)][j] = bf16(P[c-j][o]) or 0 ----------------
__global__ __launch_bounds__(256) void k_ptrib(const float* __restrict__ P,
                                               ushort_t* __restrict__ Ptrib) {
    int idx = blockIdx.x * 256 + threadIdx.x;   // (CH*ORD)*CH
    int col = idx >> 6, j = idx & (CH - 1);
    int c = col >> 8, o = col & 255;
    float v = (j <= c) ? P[(size_t)(c - j) * ORD + o] : 0.f;
    Ptrib[idx] = f2bf(v);
}

// ---------------- Apb[col=(c,o)][op] = bf16(A^{c+1}[op][o]) ----------------
__global__ __launch_bounds__(256) void k_apb(const float* __restrict__ Apow,
                                             ushort_t* __restrict__ Apb) {
    int idx = blockIdx.x * 256 + threadIdx.x;   // (CH*ORD)*ORD
    int col = idx >> 8, op = idx & 255;
    int c = col >> 8, o = col & 255;
    Apb[idx] = f2bf(Apow[(size_t)(c + 1) * OO + (size_t)op * ORD + o]);
}

// ---------------- Whbt[col][k] = bf16(Wh[k][col]) ----------------
__global__ __launch_bounds__(256) void k_whbt(const float* __restrict__ Wh,
                                              ushort_t* __restrict__ Whbt) {
    int idx = blockIdx.x * 256 + threadIdx.x;   // HID*DO
    int col = idx >> 11, k = idx & (DO - 1);
    Whbt[idx] = f2bf(Wh[(size_t)k * HID + col]);
}

// ---------------- Mqb = bf16(Mq) ----------------
__global__ __launch_bounds__(256) void k_mqb(const float* __restrict__ Mq,
                                             ushort_t* __restrict__ Mqb) {
    int idx = blockIdx.x * 256 + threadIdx.x;   // NQ*BD*ORD
    Mqb[idx] = f2bf(Mq[idx]);
}

// ---------------- Lend[q,bd,o] = sum_j U2[bd,qC+j] * P[CH-1-j,o]  (f32) ----
__global__ __launch_bounds__(256) void k_lend(const float* __restrict__ U2,
                                              const float* __restrict__ P,
                                              float* __restrict__ Lend) {
    __shared__ float As[16][65];
    __shared__ float Bs[16][65];
    const int q    = blockIdx.z;
    const int row0 = blockIdx.y * 64;
    const int col0 = blockIdx.x * 64;
    const int tid  = threadIdx.x;
    const int tx = tid & 15, ty = tid >> 4;

    float acc[4][4] = {};
    for (int k0 = 0; k0 < CH; k0 += 16) {
        for (int i = tid; i < 64 * 16; i += 256) {
            int m = i >> 4, kk = i & 15;
            As[kk][m] = U2[(size_t)(row0 + m) * T + q * CH + k0 + kk];
        }
        for (int i = tid; i < 16 * 64; i += 256) {
            int kk = i >> 6, n2 = i & 63;
            Bs[kk][n2] = P[(size_t)(CH - 1 - (k0 + kk)) * ORD + col0 + n2];
        }
        __syncthreads();
        #pragma unroll
        for (int kk = 0; kk < 16; ++kk) {
            float a[4], b[4];
            #pragma unroll
            for (int i = 0; i < 4; ++i) a[i] = As[kk][ty * 4 + i];
            #pragma unroll
            for (int j = 0; j < 4; ++j) b[j] = Bs[kk][tx * 4 + j];
            #pragma unroll
            for (int i = 0; i < 4; ++i)
                #pragma unroll
                for (int j = 0; j < 4; ++j) acc[i][j] += a[i] * b[j];
        }
        __syncthreads();
    }
    #pragma unroll
    for (int i = 0; i < 4; ++i) {
        float4 v = make_float4(acc[i][0], acc[i][1], acc[i][2], acc[i][3]);
        *(float4*)&Lend[(size_t)q * (BD * ORD) +
                        (size_t)(row0 + ty * 4 + i) * ORD + col0 + tx * 4] = v;
    }
}

// ---------------- scan init: M[0]=0, M[q]=Lend[q-1] ----------------
__global__ __launch_bounds__(256) void k_scaninit(const float* __restrict__ Lend,
                                                  float* __restrict__ M) {
    int idx = blockIdx.x * 256 + threadIdx.x;   // NQ*BD*ORD
    int q = idx >> 16;                          // BD*ORD = 65536
    M[idx] = (q == 0) ? 0.f : Lend[idx - (BD * ORD)];
}

// ---------------- scan step: Mout[q] = Min[q] + Min[q-stride] @ Pw ----------
__global__ __launch_bounds__(256) void k_scan(const float* __restrict__ Min,
                                              float* __restrict__ Mout,
                                              const float* __restrict__ Pw,
                                              int stride) {
    const int q    = blockIdx.z;
    const int row0 = blockIdx.y * 64;
    const int col0 = blockIdx.x * 64;
    const int tid  = threadIdx.x;
    const float* src = Min + (size_t)q * (BD * ORD);
    float*       dst = Mout + (size_t)q * (BD * ORD);

    if (q - stride < 1) {   // nothing to add (M_0 = 0 source) -> copy through
        for (int i = tid; i < 64 * 64; i += 256) {
            int r = i >> 6, c = i & 63;
            dst[(size_t)(row0 + r) * ORD + col0 + c] =
                src[(size_t)(row0 + r) * ORD + col0 + c];
        }
        return;
    }

    __shared__ float As[16][65];
    __shared__ float Bs[16][65];
    const int tx = tid & 15, ty = tid >> 4;
    const float* Ag = Min + (size_t)(q - stride) * (BD * ORD);

    float acc[4][4] = {};
    for (int k0 = 0; k0 < ORD; k0 += 16) {
        for (int i = tid; i < 64 * 16; i += 256) {
            int m = i >> 4, kk = i & 15;
            As[kk][m] = Ag[(size_t)(row0 + m) * ORD + k0 + kk];
        }
        for (int i = tid; i < 16 * 64; i += 256) {
            int kk = i >> 6, n2 = i & 63;
            Bs[kk][n2] = Pw[(size_t)(k0 + kk) * ORD + col0 + n2];
        }
        __syncthreads();
        #pragma unroll
        for (int kk = 0; kk < 16; ++kk) {
            float a[4], b[4];
            #pragma unroll
            for (int i = 0; i < 4; ++i) a[i] = As[kk][ty * 4 + i];
            #pragma unroll
            for (int j = 0; j < 4; ++j) b[j] = Bs[kk][tx * 4 + j];
            #pragma unroll
            for (int i = 0; i < 4; ++i)
                #pragma unroll
                for (int j = 0; j < 4; ++j) acc[i][j] += a[i] * b[j];
        }
        __syncthreads();
    }
    #pragma unroll
    for (int i = 0; i < 4; ++i) {
        int row = row0 + ty * 4 + i;
        #pragma unroll
        for (int j = 0; j < 4; ++j) {
            int o = col0 + tx * 4 + j;
            dst[(size_t)row * ORD + o] =
                acc[i][j] + src[(size_t)row * ORD + o];
        }
    }
}

// ====== MFMA GEMM 1: mbuf = [U2chunk | Mq] @ [Ptrib ; Apb]  (K=320) ======
__global__ __launch_bounds__(256) void k_gemm24(const ushort_t* __restrict__ U2b,
                                                const ushort_t* __restrict__ Mqb,
                                                const ushort_t* __restrict__ Ptrib,
                                                const ushort_t* __restrict__ Apb,
                                                ushort_t* __restrict__ mbuf,
                                                int gbase, int nrows) {
    __shared__ ushort_t Als[128][40];
    __shared__ ushort_t Bls[128][40];
    const int q       = blockIdx.z;
    const int rowbase = blockIdx.y * 128;
    const int colbase = blockIdx.x * 128;
    const int tid  = threadIdx.x;
    const int lane = tid & 63;
    const int wid  = tid >> 6;
    const int wr = wid >> 1, wc = wid & 1;
    const int lr = lane & 15, lk = (lane >> 4) * 8;

    f32x4 acc[4][4];
    #pragma unroll
    for (int m = 0; m < 4; ++m)
        #pragma unroll
        for (int n = 0; n < 4; ++n) acc[m][n] = 0.f;

    for (int s = 0; s < KTOT24 / 32; ++s) {
        const int k0 = s * 32;
        #pragma unroll
        for (int i = 0; i < 2; ++i) {
            int f = tid + i * 256;
            int row = f >> 2, kv = (f & 3) * 8;
            int r2 = rowbase + row; if (r2 >= nrows) r2 = 0;
            us8 va, vb;
            if (k0 < CH) {
                va = *(const us8*)&U2b[(size_t)(gbase + r2) * T + q * CH + k0 + kv];
                vb = *(const us8*)&Ptrib[(size_t)(colbase + row) * CH + k0 + kv];
            } else {
                va = *(const us8*)&Mqb[((size_t)q * BD + gbase + r2) * ORD + (k0 - CH) + kv];
                vb = *(const us8*)&Apb[(size_t)(colbase + row) * ORD + (k0 - CH) + kv];
            }
            *(us8*)&Als[row][kv] = va;
            *(us8*)&Bls[row][kv] = vb;
        }
        __syncthreads();
        bf16x8 af[4], bfv[4];
        #pragma unroll
        for (int m = 0; m < 4; ++m) af[m]  = *(const bf16x8*)&Als[wr * 64 + m * 16 + lr][lk];
        #pragma unroll
        for (int n = 0; n < 4; ++n) bfv[n] = *(const bf16x8*)&Bls[wc * 64 + n * 16 + lr][lk];
        #pragma unroll
        for (int m = 0; m < 4; ++m)
            #pragma unroll
            for (int n = 0; n < 4; ++n)
                acc[m][n] = __builtin_amdgcn_mfma_f32_16x16x32_bf16(af[m], bfv[n], acc[m][n], 0, 0, 0);
        __syncthreads();
    }

    #pragma unroll
    for (int m = 0; m < 4; ++m) {
        #pragma unroll
        for (int n = 0; n < 4; ++n) {
            int colv = colbase + wc * 64 + n * 16 + lr;
            int c = colv >> 8, o = colv & 255;
            #pragma unroll
            for (int r = 0; r < 4; ++r) {
                int grow = rowbase + wr * 64 + m * 16 + ((lane >> 4) << 2) + r;
                if (grow < nrows) {
                    int bl = grow >> 3, d = grow & 7;
                    mbuf[((size_t)(bl * T + q * CH + c)) * DO + (d << 8) + o] =
                        f2bf(acc[m][n][r]);
                }
            }
        }
    }
}

// ====== MFMA GEMM 2: out = tanh(mbuf @ Wh + bh) ======
// 512 threads, BM=128, BN=256. Wave grid 2x4, 64x64 per wave.
__global__ __launch_bounds__(512) void k_gemm5(const ushort_t* __restrict__ mbuf,
                                               const ushort_t* __restrict__ Whbt,
                                               const float* __restrict__ bh,
                                               float* __restrict__ out) {
    __shared__ ushort_t As[128][44];
    __shared__ ushort_t Bs[256][44];
    const int rowbase = blockIdx.y * 128;
    const int colbase = blockIdx.x * 256;
    const int tid  = threadIdx.x;
    const int lane = tid & 63;
    const int wid  = tid >> 6;          // 0..7
    const int wr = wid >> 2, wc = wid & 3;
    const int lr = lane & 15, lk = (lane >> 4) * 8;

    f32x4 acc[4][4];
    #pragma unroll
    for (int m = 0; m < 4; ++m)
        #pragma unroll
        for (int n = 0; n < 4; ++n) acc[m][n] = 0.f;

    const int lrow = tid >> 2;          // 0..127
    const int lch  = (tid & 3) * 8;     // 0,8,16,24

    for (int s = 0; s < DO / 32; ++s) {
        const int k0 = s * 32;
        *(us8*)&As[lrow][lch] =
            *(const us8*)&mbuf[(size_t)(rowbase + lrow) * DO + k0 + lch];
        #pragma unroll
        for (int i = 0; i < 2; ++i) {
            int row = i * 128 + lrow;
            *(us8*)&Bs[row][lch] =
                *(const us8*)&Whbt[(size_t)(colbase + row) * DO + k0 + lch];
        }
        __syncthreads();
        bf16x8 af[4], bfv[4];
        #pragma unroll
        for (int m = 0; m < 4; ++m) af[m]  = *(const bf16x8*)&As[wr * 64 + m * 16 + lr][lk];
        #pragma unroll
        for (int n = 0; n < 4; ++n) bfv[n] = *(const bf16x8*)&Bs[wc * 64 + n * 16 + lr][lk];
        #pragma unroll
        for (int m = 0; m < 4; ++m)
            #pragma unroll
            for (int n = 0; n < 4; ++n)
                acc[m][n] = __builtin_amdgcn_mfma_f32_16x16x32_bf16(af[m], bfv[n], acc[m][n], 0, 0, 0);
        __syncthreads();
    }

    #pragma unroll
    for (int m = 0; m < 4; ++m) {
        #pragma unroll
        for (int n = 0; n < 4; ++n) {
            int col = colbase + wc * 64 + n * 16 + lr;
            float bias = bh[col];
            #pragma unroll
            for (int r = 0; r < 4; ++r) {
                int grow = rowbase + wr * 64 + m * 16 + ((lane >> 4) << 2) + r;
                out[(size_t)grow * HID + col] = tanhf(acc[m][n][r] + bias);
            }
        }
    }
}

// ---------------- launch ----------------
extern "C" void kernel_launch(void* const* d_in, const int* in_sizes, int n_in,
                              void* d_out, int out_size, void* d_ws, size_t ws_size,
                              hipStream_t stream) {
    const float* x    = (const float*)d_in[0];
    const float* kern = (const float*)d_in[1];
    const float* Wh   = (const float*)d_in[2];
    const float* bh   = (const float*)d_in[3];
    const float* A    = (const float*)d_in[4];
    const float* Brow = (const float*)d_in[5];
    float* out = (float*)d_out;

    char* base = (char*)d_ws;
    float*    U2    = (float*)(base + OFF_U2);
    float*    P     = (float*)(base + OFF_P);
    float*    Apow  = (float*)(base + OFF_APOW);
    float*    MqA   = (float*)(base + OFF_MQ);
    float*    Lend  = (float*)(base + OFF_LEND);     // also scan ping buffer
    ushort_t* U2b   = (ushort_t*)(base + OFF_U2B);
    ushort_t* Ptrib = (ushort_t*)(base + OFF_PTRB);
    ushort_t* Apb   = (ushort_t*)(base + OFF_APB);
    ushort_t* Whbt  = (ushort_t*)(base + OFF_WHBT);
    ushort_t* Mqb   = (ushort_t*)(base + OFF_MQB);
    ushort_t* mbuf  = (ushort_t*)(base + OFF_MBUF);

    // scratch for higher powers (regions dead by the time they're written)
    float* A64  = Apow + (size_t)CH * OO;  // A^64 (slot 64)
    float* A128 = Apow;                    // Apow slot 0 (unused)
    float* A256 = U2;                      // U2 f32 dead after k_lend
    float* A512 = U2 + OO;

    // choose largest batch group whose bf16 mbuf fits
    int G = 1;
    for (int g = 32; g >= 1; g >>= 1) {
        if (OFF_MBUF + (size_t)g * T * DO * 2 <= ws_size) { G = g; break; }
    }
    const int ngroups = BSZ / G;

    // U projection (f32 + bf16)
    k_u<<<dim3(BSZ * (T / 32)), 256, 0, stream>>>(x, kern, U2, U2b);

    // A powers 1..64 by doubling (f32)
    k_copyA<<<dim3(OO / 256), 256, 0, stream>>>(A, Apow);
    for (int n = 1; n < CH; n <<= 1)
        k_pow<<<dim3(4, 4, n), 256, 0, stream>>>(Apow, n);

    // P rows (f32), bf16 operand prep
    k_p<<<dim3(CH), 256, 0, stream>>>(Brow, Apow, P);
    k_ptrib<<<dim3((CH * ORD * CH) / 256), 256, 0, stream>>>(P, Ptrib);
    k_apb<<<dim3((CH * ORD * ORD) / 256), 256, 0, stream>>>(Apow, Apb);
    k_whbt<<<dim3((HID * DO) / 256), 256, 0, stream>>>(Wh, Whbt);

    // chunk-end partials (f32) — last use of U2 f32
    k_lend<<<dim3(ORD / 64, BD / 64, NQ), 256, 0, stream>>>(U2, P, Lend);

    // Hillis-Steele matrix scan for M_q (f32), strides 1,2,4,8
    k_scaninit<<<dim3((NQ * BD * ORD) / 256), 256, 0, stream>>>(Lend, MqA);
    k_sq<<<dim3(4, 4), 256, 0, stream>>>(A64,  A64,  A128);
    k_sq<<<dim3(4, 4), 256, 0, stream>>>(A128, A128, A256);
    k_sq<<<dim3(4, 4), 256, 0, stream>>>(A256, A256, A512);
    k_scan<<<dim3(4, 4, NQ), 256, 0, stream>>>(MqA, Lend, A64, 1);
    k_scan<<<dim3(4, 4, NQ), 256, 0, stream>>>(Lend, MqA, A128, 2);
    k_scan<<<dim3(4, 4, NQ), 256, 0, stream>>>(MqA, Lend, A256, 4);
    k_scan<<<dim3(4, 4, NQ), 256, 0, stream>>>(Lend, MqA, A512, 8);
    k_mqb<<<dim3((NQ * BD * ORD) / 256), 256, 0, stream>>>(MqA, Mqb);

    // per batch-group: MFMA m-materialization + MFMA output GEMM
    for (int g = 0; g < ngroups; ++g) {
        const int gbase = g * G * MD;
        const int nrows = G * MD;
        const int gy    = (nrows + 127) / 128;
        k_gemm24<<<dim3((CH * ORD) / 128, gy, NQ), 256, 0, stream>>>(
            U2b, Mqb, Ptrib, Apb, mbuf, gbase, nrows);
        k_gemm5<<<dim3(HID / 256, (G * T) / 128), 512, 0, stream>>>(
            mbuf, Whbt, bh, out + (size_t)g * G * T * HID);
    }
}